// Round 7
// baseline (257.376 us; speedup 1.0000x reference)
//
#include <hip/hip_runtime.h>
#include <hip/hip_bf16.h>
#include <stdint.h>

#define BB 16
#define SS 4096
#define CC 512
#define NTOK (BB * SS)
#define LOSS_BLOCKS 768
#define BPB (LOSS_BLOCKS / BB)     // 48 blocks per batch
#define WPBATCH (BPB * 4)          // 192 waves per batch
#define GSTRIDE (WPBATCH * 4)      // 768: stride between a wave's 4-token groups
#define MAXG 6                     // ceil(4096/768) groups max
#define DEPTH 3
#define SLOT_F4 256                // 4 KB per slot

// ws layout: cursors[16] int @0 ; idxbuf[NTOK] int @128 ; partial[768] float @128+NTOK*4

// wait until at most N vmem ops outstanding (assembler encodes the immediate)
#define WAITV(N) asm volatile("s_waitcnt vmcnt(" #N ")" ::: "memory")

__device__ __forceinline__ void stage16(const void* g, void* l) {
    auto* gp = reinterpret_cast<const uint32_t __attribute__((address_space(1)))*>(
        reinterpret_cast<uintptr_t>(g));
    auto* lp = reinterpret_cast<uint32_t __attribute__((address_space(3)))*>(
        reinterpret_cast<uintptr_t>(l));
    __builtin_amdgcn_global_load_lds(gp, lp, 16, 0, 0);  // dest = lds base + lane*16
}

// stage one token's 4 KB (2 KB logits + 2 KB target) into an LDS slot: 4 DMA instrs
__device__ __forceinline__ void stage_token(const float* __restrict__ logits,
                                            const float* __restrict__ target,
                                            int tok, void* slot, int lane) {
    const char* lrow = (const char*)(logits + (size_t)tok * CC) + lane * 16;
    const char* trow = (const char*)(target + (size_t)tok * CC) + lane * 16;
    char* s = (char*)slot;
    stage16(lrow,        s);
    stage16(lrow + 1024, s + 1024);
    stage16(trow,        s + 2048);
    stage16(trow + 1024, s + 3072);
}

// Phase A: compact active token indices into per-batch lists (unchanged r6).
__global__ __launch_bounds__(256) void compact_kernel(
    const int* __restrict__ mask,
    int*       __restrict__ idxbuf,
    int*       __restrict__ cursors) {
    const int t     = blockIdx.x * 256 + threadIdx.x;
    const int batch = blockIdx.x / 16;
    const int lane  = threadIdx.x & 63;
    const int wave  = threadIdx.x >> 6;

    const bool active = (mask[t] == 1);
    unsigned long long ball = __ballot(active);
    const int prefix = __popcll(ball & ((1ull << lane) - 1ull));
    const int wcount = __popcll(ball);

    __shared__ int wbase[4];
    __shared__ int blockbase;
    if (lane == 0) wbase[wave] = wcount;
    __syncthreads();
    if (threadIdx.x == 0) {
        int total = wbase[0] + wbase[1] + wbase[2] + wbase[3];
        blockbase = atomicAdd(&cursors[batch], total);
        int s = 0;
        for (int i = 0; i < 4; ++i) { int c = wbase[i]; wbase[i] = s; s += c; }
    }
    __syncthreads();
    if (active)
        idxbuf[batch * SS + blockbase + wbase[wave] + prefix] = t;
}

// Phase B: per-wave 3-slot LDS ring, global_load_lds staging 2 tokens ahead,
// vmcnt(8/4/0) waits. Loop contains NO other vmem: indices live in one
// lane-mapped register (lane i holds this wave's i-th token), fetched via shfl.
__global__ __launch_bounds__(256) void loss_kernel(
    const float* __restrict__ logits,
    const float* __restrict__ target,
    const int*   __restrict__ idxbuf,
    const int*   __restrict__ cursors,
    float*       __restrict__ partial) {
    __shared__ float4 ring[4][DEPTH][SLOT_F4];   // 48 KB
    __shared__ float  ls[4];

    const int wave  = threadIdx.x >> 6;
    const int lane  = threadIdx.x & 63;
    const int batch = blockIdx.x / BPB;
    const int wib   = (blockIdx.x % BPB) * 4 + wave;   // 0..191
    const int cnt   = cursors[batch];
    const int* list = idxbuf + batch * SS;

    // lane l (<24) holds list index k_l = wib*4 + (l>>2)*GSTRIDE + (l&3):
    // this wave's l-th token, monotone in l -> validity is a prefix.
    int myidx = 0;
    if (lane < 4 * MAXG)
        myidx = list[wib * 4 + (lane >> 2) * GSTRIDE + (lane & 3)];

    int nt = 0;
    #pragma unroll
    for (int g = 0; g < MAXG; ++g) {
        int v = cnt - (wib * 4 + g * GSTRIDE);
        nt += (v < 0) ? 0 : (v > 4 ? 4 : v);
    }

    if (nt > 0) stage_token(logits, target, __shfl(myidx, 0, 64), &ring[wave][0][0], lane);
    if (nt > 1) stage_token(logits, target, __shfl(myidx, 1, 64), &ring[wave][1][0], lane);

    float dotAcc = 0.0f, logAcc = 0.0f;
    int s0 = 0, s2 = 2;
    for (int i = 0; i < nt; ++i) {
        if (i + 2 < nt) {
            stage_token(logits, target, __shfl(myidx, i + 2, 64), &ring[wave][s2][0], lane);
            WAITV(8);          // 12 outstanding -> retire oldest 4 = slot s0
        } else if (i + 1 < nt) {
            WAITV(4);
        } else {
            WAITV(0);
        }
        const float4* sl = (const float4*)&ring[wave][s0][0];
        float4 x0 = sl[lane];
        float4 x1 = sl[lane + 64];
        float4 t0 = sl[lane + 128];
        float4 t1 = sl[lane + 192];
        float se = __expf(x0.x) + __expf(x0.y) + __expf(x0.z) + __expf(x0.w)
                 + __expf(x1.x) + __expf(x1.y) + __expf(x1.z) + __expf(x1.w);
        dotAcc += t0.x * x0.x + t0.y * x0.y + t0.z * x0.z + t0.w * x0.w
                + t1.x * x1.x + t1.y * x1.y + t1.z * x1.z + t1.w * x1.w;
        #pragma unroll
        for (int off = 32; off >= 1; off >>= 1)
            se += __shfl_xor(se, off, 64);
        logAcc += __logf(se);
        s0 = (s0 == 2) ? 0 : s0 + 1;
        s2 = (s2 == 2) ? 0 : s2 + 1;
    }

    #pragma unroll
    for (int off = 32; off >= 1; off >>= 1)
        dotAcc += __shfl_xor(dotAcc, off, 64);

    if (lane == 0) ls[wave] = logAcc - dotAcc;
    __syncthreads();
    if (threadIdx.x == 0)
        partial[blockIdx.x] = ls[0] + ls[1] + ls[2] + ls[3];
}

// 16 waves: wave w reduces batch w's 48 partials; thread 0 averages non-empty batches.
__global__ __launch_bounds__(1024) void finalize_kernel(
    const float* __restrict__ partial,
    const int*   __restrict__ cursors,
    float*       __restrict__ out) {
    const int wave = threadIdx.x >> 6;
    const int lane = threadIdx.x & 63;

    float s = (lane < BPB) ? partial[wave * BPB + lane] : 0.0f;
    #pragma unroll
    for (int off = 32; off >= 1; off >>= 1)
        s += __shfl_xor(s, off, 64);

    __shared__ float pb[BB], has[BB];
    if (lane == 0) {
        float c = (float)cursors[wave];
        pb[wave]  = (c > 0.0f) ? s / c : 0.0f;
        has[wave] = (c > 0.0f) ? 1.0f : 0.0f;
    }
    __syncthreads();
    if (threadIdx.x == 0) {
        float acc = 0.0f, nb = 0.0f;
        for (int b = 0; b < BB; ++b) { acc += pb[b]; nb += has[b]; }
        out[0] = acc / fmaxf(nb, 1.0f);
    }
}

extern "C" void kernel_launch(void* const* d_in, const int* in_sizes, int n_in,
                              void* d_out, int out_size, void* d_ws, size_t ws_size,
                              hipStream_t stream) {
    const float* logits = (const float*)d_in[0];
    const float* target = (const float*)d_in[1];
    const int*   mask   = (const int*)d_in[2];
    float* out     = (float*)d_out;
    int*   cursors = (int*)d_ws;
    int*   idxbuf  = (int*)((char*)d_ws + 128);
    float* partial = (float*)((char*)d_ws + 128 + NTOK * 4);

    hipMemsetAsync(cursors, 0, 64, stream);
    compact_kernel<<<NTOK / 256, 256, 0, stream>>>(mask, idxbuf, cursors);
    loss_kernel<<<LOSS_BLOCKS, 256, 0, stream>>>(logits, target, idxbuf, cursors, partial);
    finalize_kernel<<<1, 1024, 0, stream>>>(partial, cursors, out);
}